// Round 15
// baseline (292.813 us; speedup 1.0000x reference)
//
#include <hip/hip_runtime.h>
#include <hip/hip_fp16.h>
#include <type_traits>

#define NPOI 50000
#define EMB 128
#define NEDGE 800000
#define EAUG (2 * NEDGE + NPOI)
#define BATCH 512
#define SEQL 64
#define NHEADS 4
#define HDIM 32
#define NB 196                              // 256-node buckets
#define P1_BLOCKS ((NEDGE + 2047) / 2048)   // 391
#define SLAB_CAP 10240
#define BUCKET_CAP 10240

typedef _Float16 half8 __attribute__((ext_vector_type(8)));
typedef _Float16 half4 __attribute__((ext_vector_type(4)));
typedef _Float16 half2t __attribute__((ext_vector_type(2)));
typedef float f32x4 __attribute__((ext_vector_type(4)));
typedef unsigned long long u64;

union HBits { _Float16 h; unsigned short u; };

// ---------------- fp32 -> fp16 convert (lin_w, in_proj_w only) + bcur init ----------------

#define N4_LIN (2 * 128 * 128 / 4)
#define N4_INW (384 * 128 / 4)
#define CVT_TOT (N4_LIN + N4_INW + NB)

__global__ void cvt_all_kernel(const float* __restrict__ linw, const float* __restrict__ inw,
                               _Float16* __restrict__ linw_h, _Float16* __restrict__ inw_h,
                               int* __restrict__ bcur) {
    int i = blockIdx.x * blockDim.x + threadIdx.x;
    const float* src; _Float16* dst; int j = i;
    if (i < N4_LIN) { src = linw; dst = linw_h; }
    else if (i < N4_LIN + N4_INW) { j = i - N4_LIN; src = inw; dst = inw_h; }
    else if (i < CVT_TOT) { int b = i - (N4_LIN + N4_INW); bcur[b] = b * SLAB_CAP; return; }
    else return;
    float4 v = ((const float4*)src)[j];
    half4 h = { (_Float16)v.x, (_Float16)v.y, (_Float16)v.z, (_Float16)v.w };
    ((half4*)dst)[j] = h;
}

// ---------------- phase 1: LDS-buffered multisplit into static per-bucket slabs ----------------

__global__ __launch_bounds__(256) void partition_kernel(
    const int* __restrict__ e0, const int* __restrict__ e1,
    const float* __restrict__ dv, int* __restrict__ bcur,
    u64* __restrict__ staging)
{
    __shared__ u64 stg[4096];
    __shared__ int lh[NB], lbase[NB], gb[NB];
    __shared__ int sc[256];
    const int t = threadIdx.x;
    const int blockBase = blockIdx.x * 2048;
    for (int j = t; j < NB; j += 256) lh[j] = 0;
    __syncthreads();

    u64 vals[16];
    unsigned br[16];
#pragma unroll
    for (int i = 0; i < 8; ++i) {
        br[2 * i] = 0xFFFFFFFFu;
        br[2 * i + 1] = 0xFFFFFFFFu;
        int g = blockBase + i * 256 + t;
        if (g < NEDGE) {
            int s = e0[g], d = e1[g];
            unsigned db = __float_as_uint(dv[g]);
            vals[2 * i]     = ((u64)s << 48) | ((u64)d << 32) | db;
            vals[2 * i + 1] = ((u64)d << 48) | ((u64)s << 32) | db;
            int bs = s >> 8, bd = d >> 8;
            int rs = atomicAdd(&lh[bs], 1);
            int rd_ = atomicAdd(&lh[bd], 1);
            br[2 * i]     = ((unsigned)bs << 16) | (unsigned)rs;
            br[2 * i + 1] = ((unsigned)bd << 16) | (unsigned)rd_;
        }
    }
    __syncthreads();
    sc[t] = (t < NB) ? lh[t] : 0;
    __syncthreads();
    for (int o = 1; o < 256; o <<= 1) {
        int u = (t >= o) ? sc[t - o] : 0;
        __syncthreads();
        sc[t] += u;
        __syncthreads();
    }
    if (t < NB) {
        lbase[t] = sc[t] - lh[t];
        gb[t] = (lh[t] > 0) ? atomicAdd(&bcur[t], lh[t]) : 0;
    }
    __syncthreads();
#pragma unroll
    for (int i = 0; i < 16; ++i) {
        if (br[i] != 0xFFFFFFFFu) {
            int b = br[i] >> 16, r = br[i] & 0xFFFF;
            stg[lbase[b] + r] = vals[i];
        }
    }
    __syncthreads();
    const int total = sc[255];
    for (int j = t; j < total; j += 256) {
        u64 v = stg[j];
        int b = (int)(v >> 56);
        staging[(size_t)gb[b] + (unsigned)(j - lbase[b])] = v;
    }
}

// ---------------- per-bucket counting sort + rd + offs + weights -> packed CSR ----------------
// Edge weight stores rd[s]*exp(-dist^2) only; rd[d] is folded into h via the GEMM epilogue.

__global__ __launch_bounds__(256) void csr_sort_kernel(
    const u64* __restrict__ staging, const int* __restrict__ bcur,
    float* __restrict__ rd, int* __restrict__ offs, unsigned* __restrict__ ew)
{
    const int k = blockIdx.x;
    const int node0 = k * 256;
    __shared__ unsigned outb[BUCKET_CAP];
    __shared__ int cnt[256], base2[256];
    __shared__ float rdl[256];
    __shared__ int bb_sh;
    const int t = threadIdx.x;
    const int node = node0 + t;
    // bucket base = sum over previous buckets of (slab fill + 256 self loops)
    {
        int partial = 0;
        for (int j = t; j < k; j += 256) partial += (bcur[j] - j * SLAB_CAP) + 256;
        base2[t] = partial;
        __syncthreads();
        for (int o = 128; o > 0; o >>= 1) {
            if (t < o) base2[t] += base2[t + o];
            __syncthreads();
        }
        if (t == 0) bb_sh = base2[0];
        __syncthreads();
    }
    const int bucketbase = bb_sh;
    __syncthreads();
    cnt[t] = 0;
    __syncthreads();
    const int sb = k * SLAB_CAP;
    const int n = bcur[k] - sb;
    for (int j = t; j < n; j += 256)
        atomicAdd(&cnt[(int)(staging[sb + j] >> 48) & 255], 1);
    __syncthreads();
    int rowsz = (node < NPOI) ? cnt[t] + 1 : 0;
    if (node < NPOI) {
        float r_ = rsqrtf((float)rowsz);
        rd[node] = r_;
        rdl[t] = r_;
    } else rdl[t] = 0.f;
    base2[t] = rowsz;
    __syncthreads();
    for (int o = 1; o < 256; o <<= 1) {
        int u = (t >= o) ? base2[t - o] : 0;
        __syncthreads();
        base2[t] += u;
        __syncthreads();
    }
    int myexc = base2[t] - rowsz;
    __syncthreads();
    base2[t] = myexc;
    cnt[t] = 0;
    if (node < NPOI) {
        offs[node] = bucketbase + myexc;
        if (node == NPOI - 1) offs[NPOI] = bucketbase + myexc + rowsz;
    }
    __syncthreads();
    for (int j = t; j < n; j += 256) {
        u64 e = staging[sb + j];
        int sl = (int)(e >> 48) & 255;
        int d = (int)(e >> 32) & 0xFFFF;
        float dist = __uint_as_float((unsigned)e);
        float w = rdl[sl] * expf(-dist * dist);      // rd[d] folded into h'
        HBits cv; cv.h = (_Float16)w;
        int r = atomicAdd(&cnt[sl], 1);
        outb[base2[sl] + r] = ((unsigned)d << 16) | cv.u;
    }
    __syncthreads();
    if (node < NPOI) {   // self loop: w' = rd[s] (h'[s] carries the other rd[s])
        HBits cv; cv.h = (_Float16)rdl[t];
        outb[base2[t] + cnt[t]] = ((unsigned)node << 16) | cv.u;
    }
    __syncthreads();
    const int ntot = n + ((node0 + 256 <= NPOI) ? 256 : (NPOI - node0));
    for (int j = t; j < ntot; j += 256) ew[bucketbase + j] = outb[j];   // coalesced
}

// ---------------- fp16 MFMA GEMM, 128x64 tile: C = rs(row)·(A(gathered) @ B^T + bias) ----------
// A dtype templated: fp32 A is converted to fp16 during LDS staging (kills the poi pre-convert).
// 4 waves; wave w = cols [w*16,w*16+16), rows 0..127 in 8 mt-tiles; 32 MFMA / 36 ds_read per wave.

template <typename AT>
__global__ __launch_bounds__(256) void gemm_mfma_f16(
    const AT* __restrict__ A, const int* __restrict__ gidx,
    const _Float16* __restrict__ B, const float* __restrict__ bias,
    const float* __restrict__ rs,
    _Float16* __restrict__ C, int M, int N)
{
    __shared__ _Float16 Asl[128][136];   // 34.8 KB
    __shared__ _Float16 Bsl[64][136];    // 17.4 KB  (total 52.2 KB -> 3 blocks/CU)
    const int tid = threadIdx.x;
    const int n0 = blockIdx.x * 64;
    const int m0 = blockIdx.y * 128;

    if constexpr (std::is_same<AT, _Float16>::value) {
        // 128 rows x 16 chunks (8 halves) = 2048 units
#pragma unroll
        for (int i = 0; i < 8; ++i) {
            int u = i * 256 + tid;
            int r = u >> 4, c = u & 15;
            int row = m0 + r;
            int ar = (row < M) ? (gidx ? gidx[row] : row) : 0;
            *(float4*)&Asl[r][c * 8] = *(const float4*)(A + (size_t)ar * 128 + c * 8);
        }
    } else {
        // fp32: 128 rows x 32 chunks (4 floats) = 4096 units; convert in-flight
#pragma unroll
        for (int i = 0; i < 16; ++i) {
            int u = i * 256 + tid;
            int r = u >> 5, c = u & 31;
            int row = m0 + r;
            int ar = (row < M) ? (gidx ? gidx[row] : row) : 0;
            float4 v = *(const float4*)(A + (size_t)ar * 128 + c * 4);
            half4 h = { (_Float16)v.x, (_Float16)v.y, (_Float16)v.z, (_Float16)v.w };
            *(half4*)&Asl[r][c * 4] = h;
        }
    }
    // B: 64 rows x 16 chunks = 1024 units
#pragma unroll
    for (int i = 0; i < 4; ++i) {
        int u = i * 256 + tid;
        int r = u >> 4, c = u & 15;
        *(float4*)&Bsl[r][c * 8] = *(const float4*)(B + (size_t)(n0 + r) * 128 + c * 8);
    }
    __syncthreads();

    const int wave = tid >> 6;
    const int lane = tid & 63;
    const int l15 = lane & 15;
    const int quad = lane >> 4;

    f32x4 acc[8];
#pragma unroll
    for (int mt = 0; mt < 8; ++mt) acc[mt] = (f32x4){0.f, 0.f, 0.f, 0.f};

#pragma unroll
    for (int ks = 0; ks < 4; ++ks) {
        half8 bfrag = *(const half8*)&Bsl[wave * 16 + l15][quad * 8 + ks * 32];
#pragma unroll
        for (int mt = 0; mt < 8; ++mt) {
            half8 afrag = *(const half8*)&Asl[mt * 16 + l15][quad * 8 + ks * 32];
            acc[mt] = __builtin_amdgcn_mfma_f32_16x16x32_f16(afrag, bfrag, acc[mt], 0, 0, 0);
        }
    }

    // transpose C tile through LDS (reuse Asl) for vectorized stores; row scale applied here
    const int col = wave * 16 + l15;
    const float bv = bias[n0 + col];
    __syncthreads();
#pragma unroll
    for (int mt = 0; mt < 8; ++mt)
#pragma unroll
        for (int r = 0; r < 4; ++r) {
            int m = m0 + mt * 16 + quad * 4 + r;
            float v = acc[mt][r] + bv;
            if (rs) { int mm = (m < M) ? m : 0; v *= rs[mm]; }
            Asl[mt * 16 + quad * 4 + r][col] = (_Float16)v;
        }
    __syncthreads();
    // 128 rows x 8 chunks (64 cols) = 1024 units; 16B/lane coalesced
#pragma unroll
    for (int i = 0; i < 4; ++i) {
        int u = i * 256 + tid;
        int r = u >> 3;
        int c = u & 7;
        int m = m0 + r;
        if (m < M)
            *(half8*)(C + (size_t)m * N + n0 + c * 8) = *(const half8*)&Asl[r][c * 8];
    }
}

// ---------------- CSR aggregate + leaky-relu + L2 normalize ----------------
// 64 threads/row; ew[e] is wave-uniform -> scalar load; 8 gathers in flight via unroll.

__global__ __launch_bounds__(64) void aggregate_kernel(
    const _Float16* __restrict__ h, const int* __restrict__ offs,
    const unsigned* __restrict__ ew, _Float16* __restrict__ enc_h)
{
    const int row = blockIdx.x;
    const int lane = threadIdx.x;
    const int beg = offs[row];
    const int end = offs[row + 1];
    float ax = 0.f, ay = 0.f;
#pragma unroll 8
    for (int e = beg; e < end; ++e) {
        unsigned p = ew[e];
        HBits cv; cv.u = (unsigned short)(p & 0xffffu);
        float w = (float)cv.h;
        int d = p >> 16;
        half2t hv = *(const half2t*)(h + (size_t)d * 128 + lane * 2);
        ax += w * (float)hv[0];
        ay += w * (float)hv[1];
    }
    ax = ax >= 0.f ? ax : 0.01f * ax;
    ay = ay >= 0.f ? ay : 0.01f * ay;
    float ss = ax * ax + ay * ay;
#pragma unroll
    for (int o = 32; o > 0; o >>= 1) ss += __shfl_xor(ss, o);
    float inv = 1.f / fmaxf(sqrtf(ss), 1e-12f);
    half2t hv = { (_Float16)(ax * inv), (_Float16)(ay * inv) };
    *(half2t*)(enc_h + (size_t)row * 128 + lane * 2) = hv;
}

// ---------------- MFMA attention + mean + out_proj + fused tar gather ----------------

__global__ __launch_bounds__(256) void attn_mfma_kernel(
    const _Float16* __restrict__ qkv, const float* __restrict__ outw,
    const float* __restrict__ outb, const _Float16* __restrict__ enc_h,
    const int* __restrict__ data_poi, float* __restrict__ out)
{
    const int b = blockIdx.x;
    const int wave = threadIdx.x >> 6;   // head
    const int lane = threadIdx.x & 63;
    const int l15 = lane & 15;
    const int quad = lane >> 4;
    __shared__ _Float16 pP[NHEADS][64][72];
    __shared__ _Float16 vT[NHEADS][32][72];
    __shared__ float ob[128];
    const _Float16* base = qkv + (size_t)b * SEQL * 384;

    // stage V^T: lane m scatters its V row
    {
        const _Float16* vrow = base + (size_t)lane * 384 + 256 + wave * 32;
        half8 v0 = *(const half8*)(vrow);
        half8 v1 = *(const half8*)(vrow + 8);
        half8 v2 = *(const half8*)(vrow + 16);
        half8 v3 = *(const half8*)(vrow + 24);
#pragma unroll
        for (int j = 0; j < 8; ++j) {
            vT[wave][j][lane]      = v0[j];
            vT[wave][j + 8][lane]  = v1[j];
            vT[wave][j + 16][lane] = v2[j];
            vT[wave][j + 24][lane] = v3[j];
        }
    }

    // Q / K fragments straight from global (A-layout: row=l15, k=quad*8+j)
    half8 qf[4], kf[4];
#pragma unroll
    for (int t = 0; t < 4; ++t) {
        qf[t] = *(const half8*)(base + (size_t)(t * 16 + l15) * 384 + wave * 32 + quad * 8);
        kf[t] = *(const half8*)(base + (size_t)(t * 16 + l15) * 384 + 128 + wave * 32 + quad * 8);
    }

    f32x4 S[4][4];
#pragma unroll
    for (int lt = 0; lt < 4; ++lt)
#pragma unroll
        for (int mt = 0; mt < 4; ++mt) S[lt][mt] = (f32x4){0.f, 0.f, 0.f, 0.f};
#pragma unroll
    for (int lt = 0; lt < 4; ++lt)
#pragma unroll
        for (int mt = 0; mt < 4; ++mt)
            S[lt][mt] = __builtin_amdgcn_mfma_f32_16x16x32_f16(qf[lt], kf[mt], S[lt][mt], 0, 0, 0);

    const float scale = 0.17677669529663687f;  // 1/sqrt(32)
#pragma unroll
    for (int lt = 0; lt < 4; ++lt) {
#pragma unroll
        for (int r = 0; r < 4; ++r) {
            float m0 = -1e30f;
#pragma unroll
            for (int mt = 0; mt < 4; ++mt) {
                S[lt][mt][r] *= scale;
                m0 = fmaxf(m0, S[lt][mt][r]);
            }
#pragma unroll
            for (int o = 1; o < 16; o <<= 1) m0 = fmaxf(m0, __shfl_xor(m0, o));
            float s0 = 0.f;
#pragma unroll
            for (int mt = 0; mt < 4; ++mt) {
                float p = __expf(S[lt][mt][r] - m0);
                S[lt][mt][r] = p;
                s0 += p;
            }
#pragma unroll
            for (int o = 1; o < 16; o <<= 1) s0 += __shfl_xor(s0, o);
            float inv = 1.f / s0;
#pragma unroll
            for (int mt = 0; mt < 4; ++mt)
                pP[wave][lt * 16 + quad * 4 + r][mt * 16 + l15] = (_Float16)(S[lt][mt][r] * inv);
        }
    }
    __syncthreads();

    // O = P V : contraction over m (64) in 2 steps
    f32x4 O[4][2];
#pragma unroll
    for (int lt = 0; lt < 4; ++lt)
#pragma unroll
        for (int jt = 0; jt < 2; ++jt) O[lt][jt] = (f32x4){0.f, 0.f, 0.f, 0.f};
#pragma unroll
    for (int kh = 0; kh < 2; ++kh) {
        half8 vf[2];
#pragma unroll
        for (int jt = 0; jt < 2; ++jt)
            vf[jt] = *(const half8*)&vT[wave][jt * 16 + l15][kh * 32 + quad * 8];
#pragma unroll
        for (int lt = 0; lt < 4; ++lt) {
            half8 pf = *(const half8*)&pP[wave][lt * 16 + l15][kh * 32 + quad * 8];
#pragma unroll
            for (int jt = 0; jt < 2; ++jt)
                O[lt][jt] = __builtin_amdgcn_mfma_f32_16x16x32_f16(pf, vf[jt], O[lt][jt], 0, 0, 0);
        }
    }

    // mean over the 64 query rows -> ob[head*32 + j]
#pragma unroll
    for (int jt = 0; jt < 2; ++jt) {
        float part = 0.f;
#pragma unroll
        for (int lt = 0; lt < 4; ++lt)
#pragma unroll
            for (int r = 0; r < 4; ++r) part += O[lt][jt][r];
        part += __shfl_xor(part, 16);
        part += __shfl_xor(part, 32);
        if (quad == 0) ob[wave * 32 + jt * 16 + l15] = part * (1.f / 64.f);
    }
    __syncthreads();

    int t = threadIdx.x;
    if (t < 128) {
        float val = outb[t];
        const float* wrow = outw + (size_t)t * 128;
#pragma unroll 8
        for (int k4 = 0; k4 < 32; ++k4) {
            float4 wv = *(const float4*)(wrow + k4 * 4);
            val += wv.x * ob[k4 * 4] + wv.y * ob[k4 * 4 + 1]
                 + wv.z * ob[k4 * 4 + 2] + wv.w * ob[k4 * 4 + 3];
        }
        out[(size_t)b * 128 + t] = val;
    } else {
        // fused tar_embed gather (fp16 enc)
        int j = t - 128;
        out[(size_t)(BATCH + b) * 128 + j] = (float)enc_h[(size_t)data_poi[b] * 128 + j];
    }
}

// ---------------- launch ----------------

extern "C" void kernel_launch(void* const* d_in, const int* in_sizes, int n_in,
                              void* d_out, int out_size, void* d_ws, size_t ws_size,
                              hipStream_t stream)
{
    const float* poi      = (const float*)d_in[0];
    const int*   edges    = (const int*)d_in[1];
    const float* dvec     = (const float*)d_in[2];
    const int*   data_poi = (const int*)d_in[3];
    const int*   data_x   = (const int*)d_in[4];
    const float* lin_w    = (const float*)d_in[5];
    const float* lin_b    = (const float*)d_in[6];
    const float* inw      = (const float*)d_in[7];
    const float* inb      = (const float*)d_in[8];
    const float* outw     = (const float*)d_in[9];
    const float* outb     = (const float*)d_in[10];
    const int* e0 = edges;
    const int* e1 = edges + NEDGE;

    char* ws = (char*)d_ws;
    size_t off = 0;
    auto alloc = [&](size_t bytes) -> void* {
        void* p = ws + off;
        off = (off + bytes + 255) & ~(size_t)255;
        return p;
    };
    int*      offs   = (int*)     alloc((NPOI + 1) * 4);
    int*      bcur   = (int*)     alloc(NB * 4);
    float*    rd     = (float*)   alloc(NPOI * 4);
    unsigned* ew     = (unsigned*)alloc((size_t)EAUG * 4);
    _Float16* enc_h  = (_Float16*)alloc((size_t)NPOI * 128 * 2);
    _Float16* linw_h = (_Float16*)alloc((size_t)2 * 128 * 128 * 2);
    _Float16* inw_h  = (_Float16*)alloc((size_t)384 * 128 * 2);
    char*     big    = (char*)    alloc(50ull * 1024 * 1024);
    // aliases inside the big region (lifetimes strictly ordered):
    //   staging [16, 32.1 MB)  — partition -> csr_sort
    //   hbuf    [33, 45.8 MB)  — GEMM1/2 -> aggregate
    //   qkv_h   [ 0, 25.2 MB)  — qkv GEMM (after staging dead) -> attn
    u64*      staging = (u64*)(big + 16ull * 1024 * 1024);
    _Float16* hbuf    = (_Float16*)(big + 33ull * 1024 * 1024);
    _Float16* qkv_h   = (_Float16*)big;

    cvt_all_kernel<<<(CVT_TOT + 255) / 256, 256, 0, stream>>>(
        lin_w, inw, linw_h, inw_h, bcur);

    partition_kernel<<<P1_BLOCKS, 256, 0, stream>>>(e0, e1, dvec, bcur, staging);
    csr_sort_kernel<<<NB, 256, 0, stream>>>(staging, bcur, rd, offs, ew);

    // 2 graph-conv layers (rd folded into h via GEMM epilogue row-scale);
    // layer-1 GEMM reads poi fp32 directly, converting during staging
    gemm_mfma_f16<float><<<dim3(2, (NPOI + 127) / 128), 256, 0, stream>>>(
        poi, nullptr, linw_h, lin_b, rd, hbuf, NPOI, 128);
    aggregate_kernel<<<NPOI, 64, 0, stream>>>(hbuf, offs, ew, enc_h);
    gemm_mfma_f16<_Float16><<<dim3(2, (NPOI + 127) / 128), 256, 0, stream>>>(
        enc_h, nullptr, linw_h + 128 * 128, lin_b + 128, rd, hbuf, NPOI, 128);
    aggregate_kernel<<<NPOI, 64, 0, stream>>>(hbuf, offs, ew, enc_h);

    // attention (qkv gemm fp16 -> MFMA attn + mean + out_proj + tar -> d_out)
    gemm_mfma_f16<_Float16><<<dim3(6, BATCH * SEQL / 128), 256, 0, stream>>>(
        enc_h, data_x, inw_h, inb, nullptr, qkv_h, BATCH * SEQL, 384);
    attn_mfma_kernel<<<BATCH, 256, 0, stream>>>(qkv_h, outw, outb, enc_h, data_poi,
                                                (float*)d_out);
}

// Round 16
// 283.481 us; speedup vs baseline: 1.0329x; 1.0329x over previous
//
#include <hip/hip_runtime.h>
#include <hip/hip_fp16.h>

#define NPOI 50000
#define EMB 128
#define NEDGE 800000
#define EAUG (2 * NEDGE + NPOI)
#define BATCH 512
#define SEQL 64
#define NHEADS 4
#define HDIM 32
#define NB 196                              // 256-node buckets
#define P1_BLOCKS ((NEDGE + 2047) / 2048)   // 391
#define SLAB_CAP 10240
#define BUCKET_CAP 10240

typedef _Float16 half8 __attribute__((ext_vector_type(8)));
typedef _Float16 half4 __attribute__((ext_vector_type(4)));
typedef _Float16 half2t __attribute__((ext_vector_type(2)));
typedef float f32x4 __attribute__((ext_vector_type(4)));
typedef unsigned long long u64;

union HBits { _Float16 h; unsigned short u; };

// ---------------- fused fp32 -> fp16 convert (poi, lin_w, in_proj_w) + bcur init ----------------

#define N4_POI (NPOI * 128 / 4)
#define N4_LIN (2 * 128 * 128 / 4)
#define N4_INW (384 * 128 / 4)
#define CVT_TOT (N4_POI + N4_LIN + N4_INW + NB)

__global__ void cvt_all_kernel(const float* __restrict__ poi, const float* __restrict__ linw,
                               const float* __restrict__ inw,
                               _Float16* __restrict__ poi_h, _Float16* __restrict__ linw_h,
                               _Float16* __restrict__ inw_h, int* __restrict__ bcur) {
    int i = blockIdx.x * blockDim.x + threadIdx.x;
    const float* src; _Float16* dst; int j = i;
    if (i < N4_POI) { src = poi; dst = poi_h; }
    else if (i < N4_POI + N4_LIN) { j = i - N4_POI; src = linw; dst = linw_h; }
    else if (i < N4_POI + N4_LIN + N4_INW) { j = i - N4_POI - N4_LIN; src = inw; dst = inw_h; }
    else if (i < CVT_TOT) { int b = i - (N4_POI + N4_LIN + N4_INW); bcur[b] = b * SLAB_CAP; return; }
    else return;
    float4 v = ((const float4*)src)[j];
    half4 h = { (_Float16)v.x, (_Float16)v.y, (_Float16)v.z, (_Float16)v.w };
    ((half4*)dst)[j] = h;
}

// ---------------- phase 1: LDS-buffered multisplit into static per-bucket slabs ----------------

__global__ __launch_bounds__(256) void partition_kernel(
    const int* __restrict__ e0, const int* __restrict__ e1,
    const float* __restrict__ dv, int* __restrict__ bcur,
    u64* __restrict__ staging)
{
    __shared__ u64 stg[4096];
    __shared__ int lh[NB], lbase[NB], gb[NB];
    __shared__ int sc[256];
    const int t = threadIdx.x;
    const int blockBase = blockIdx.x * 2048;
    for (int j = t; j < NB; j += 256) lh[j] = 0;
    __syncthreads();

    u64 vals[16];
    unsigned br[16];
#pragma unroll
    for (int i = 0; i < 8; ++i) {
        br[2 * i] = 0xFFFFFFFFu;
        br[2 * i + 1] = 0xFFFFFFFFu;
        int g = blockBase + i * 256 + t;
        if (g < NEDGE) {
            int s = e0[g], d = e1[g];
            unsigned db = __float_as_uint(dv[g]);
            vals[2 * i]     = ((u64)s << 48) | ((u64)d << 32) | db;
            vals[2 * i + 1] = ((u64)d << 48) | ((u64)s << 32) | db;
            int bs = s >> 8, bd = d >> 8;
            int rs = atomicAdd(&lh[bs], 1);
            int rd_ = atomicAdd(&lh[bd], 1);
            br[2 * i]     = ((unsigned)bs << 16) | (unsigned)rs;
            br[2 * i + 1] = ((unsigned)bd << 16) | (unsigned)rd_;
        }
    }
    __syncthreads();
    sc[t] = (t < NB) ? lh[t] : 0;
    __syncthreads();
    for (int o = 1; o < 256; o <<= 1) {
        int u = (t >= o) ? sc[t - o] : 0;
        __syncthreads();
        sc[t] += u;
        __syncthreads();
    }
    if (t < NB) {
        lbase[t] = sc[t] - lh[t];
        gb[t] = (lh[t] > 0) ? atomicAdd(&bcur[t], lh[t]) : 0;
    }
    __syncthreads();
#pragma unroll
    for (int i = 0; i < 16; ++i) {
        if (br[i] != 0xFFFFFFFFu) {
            int b = br[i] >> 16, r = br[i] & 0xFFFF;
            stg[lbase[b] + r] = vals[i];
        }
    }
    __syncthreads();
    const int total = sc[255];
    for (int j = t; j < total; j += 256) {
        u64 v = stg[j];
        int b = (int)(v >> 56);
        staging[(size_t)gb[b] + (unsigned)(j - lbase[b])] = v;
    }
}

// ---------------- per-bucket counting sort + rd + offs + weights -> packed CSR ----------------
// Edge weight stores rd[s]*exp(-dist^2) only; rd[d] is folded into h via the GEMM epilogue.

__global__ __launch_bounds__(256) void csr_sort_kernel(
    const u64* __restrict__ staging, const int* __restrict__ bcur,
    float* __restrict__ rd, int* __restrict__ offs, unsigned* __restrict__ ew)
{
    const int k = blockIdx.x;
    const int node0 = k * 256;
    __shared__ unsigned outb[BUCKET_CAP];
    __shared__ int cnt[256], base2[256];
    __shared__ float rdl[256];
    __shared__ int bb_sh;
    const int t = threadIdx.x;
    const int node = node0 + t;
    // bucket base = sum over previous buckets of (slab fill + 256 self loops)
    {
        int partial = 0;
        for (int j = t; j < k; j += 256) partial += (bcur[j] - j * SLAB_CAP) + 256;
        base2[t] = partial;
        __syncthreads();
        for (int o = 128; o > 0; o >>= 1) {
            if (t < o) base2[t] += base2[t + o];
            __syncthreads();
        }
        if (t == 0) bb_sh = base2[0];
        __syncthreads();
    }
    const int bucketbase = bb_sh;
    __syncthreads();
    cnt[t] = 0;
    __syncthreads();
    const int sb = k * SLAB_CAP;
    const int n = bcur[k] - sb;
    for (int j = t; j < n; j += 256)
        atomicAdd(&cnt[(int)(staging[sb + j] >> 48) & 255], 1);
    __syncthreads();
    int rowsz = (node < NPOI) ? cnt[t] + 1 : 0;
    if (node < NPOI) {
        float r_ = rsqrtf((float)rowsz);
        rd[node] = r_;
        rdl[t] = r_;
    } else rdl[t] = 0.f;
    base2[t] = rowsz;
    __syncthreads();
    for (int o = 1; o < 256; o <<= 1) {
        int u = (t >= o) ? base2[t - o] : 0;
        __syncthreads();
        base2[t] += u;
        __syncthreads();
    }
    int myexc = base2[t] - rowsz;
    __syncthreads();
    base2[t] = myexc;
    cnt[t] = 0;
    if (node < NPOI) {
        offs[node] = bucketbase + myexc;
        if (node == NPOI - 1) offs[NPOI] = bucketbase + myexc + rowsz;
    }
    __syncthreads();
    for (int j = t; j < n; j += 256) {
        u64 e = staging[sb + j];
        int sl = (int)(e >> 48) & 255;
        int d = (int)(e >> 32) & 0xFFFF;
        float dist = __uint_as_float((unsigned)e);
        float w = rdl[sl] * expf(-dist * dist);      // rd[d] folded into h'
        HBits cv; cv.h = (_Float16)w;
        int r = atomicAdd(&cnt[sl], 1);
        outb[base2[sl] + r] = ((unsigned)d << 16) | cv.u;
    }
    __syncthreads();
    if (node < NPOI) {   // self loop: w' = rd[s] (h'[s] carries the other rd[s])
        HBits cv; cv.h = (_Float16)rdl[t];
        outb[base2[t] + cnt[t]] = ((unsigned)node << 16) | cv.u;
    }
    __syncthreads();
    const int ntot = n + ((node0 + 256 <= NPOI) ? 256 : (NPOI - node0));
    for (int j = t; j < ntot; j += 256) ew[bucketbase + j] = outb[j];   // coalesced
}

// ---------------- fp16 MFMA GEMM, 64x64 tile: C = rs(row)·(A(gathered) @ B^T + bias) ----------

__global__ __launch_bounds__(256) void gemm_mfma_f16(
    const _Float16* __restrict__ A, const int* __restrict__ gidx,
    const _Float16* __restrict__ B, const float* __restrict__ bias,
    const float* __restrict__ rs,
    _Float16* __restrict__ C, int M, int N)
{
    __shared__ _Float16 Asl[64][136];
    __shared__ _Float16 Bsl[64][136];
    const int tid = threadIdx.x;
    const int n0 = blockIdx.x * 64;
    const int m0 = blockIdx.y * 64;

#pragma unroll
    for (int i = 0; i < 4; ++i) {
        int u = i * 256 + tid;
        int r = u >> 4;
        int c = u & 15;
        int row = m0 + r;
        int ar = (row < M) ? (gidx ? gidx[row] : row) : 0;
        *(float4*)&Asl[r][c * 8] = *(const float4*)(A + (size_t)ar * 128 + c * 8);
        *(float4*)&Bsl[r][c * 8] = *(const float4*)(B + (size_t)(n0 + r) * 128 + c * 8);
    }
    __syncthreads();

    const int wave = tid >> 6;
    const int lane = tid & 63;
    const int l15 = lane & 15;
    const int quad = lane >> 4;

    f32x4 acc[4];
#pragma unroll
    for (int mt = 0; mt < 4; ++mt) acc[mt] = (f32x4){0.f, 0.f, 0.f, 0.f};

#pragma unroll
    for (int ks = 0; ks < 4; ++ks) {
        half8 bfrag = *(const half8*)&Bsl[wave * 16 + l15][quad * 8 + ks * 32];
#pragma unroll
        for (int mt = 0; mt < 4; ++mt) {
            half8 afrag = *(const half8*)&Asl[mt * 16 + l15][quad * 8 + ks * 32];
            acc[mt] = __builtin_amdgcn_mfma_f32_16x16x32_f16(afrag, bfrag, acc[mt], 0, 0, 0);
        }
    }

    // transpose C tile through LDS (reuse Asl) for vectorized stores; row scale applied here
    const int col = wave * 16 + l15;
    const float bv = bias[n0 + col];
    __syncthreads();
#pragma unroll
    for (int mt = 0; mt < 4; ++mt)
#pragma unroll
        for (int r = 0; r < 4; ++r) {
            int m = m0 + mt * 16 + quad * 4 + r;
            float v = acc[mt][r] + bv;
            if (rs) { int mm = (m < M) ? m : 0; v *= rs[mm]; }
            Asl[mt * 16 + quad * 4 + r][col] = (_Float16)v;
        }
    __syncthreads();
    // 64 rows x 8 chunks (64 cols) = 512 units; 16B/lane coalesced
#pragma unroll
    for (int i = 0; i < 2; ++i) {
        int u = i * 256 + tid;
        int r = u >> 3;
        int c = u & 7;
        int m = m0 + r;
        if (m < M)
            *(half8*)(C + (size_t)m * N + n0 + c * 8) = *(const half8*)&Asl[r][c * 8];
    }
}

// ---------------- CSR aggregate + leaky-relu + L2 normalize ----------------
// 64 threads/row; ew[e] is wave-uniform -> scalar load; 8 gathers in flight via unroll.

__global__ __launch_bounds__(64) void aggregate_kernel(
    const _Float16* __restrict__ h, const int* __restrict__ offs,
    const unsigned* __restrict__ ew, _Float16* __restrict__ enc_h)
{
    const int row = blockIdx.x;
    const int lane = threadIdx.x;
    const int beg = offs[row];
    const int end = offs[row + 1];
    float ax = 0.f, ay = 0.f;
#pragma unroll 8
    for (int e = beg; e < end; ++e) {
        unsigned p = ew[e];
        HBits cv; cv.u = (unsigned short)(p & 0xffffu);
        float w = (float)cv.h;
        int d = p >> 16;
        half2t hv = *(const half2t*)(h + (size_t)d * 128 + lane * 2);
        ax += w * (float)hv[0];
        ay += w * (float)hv[1];
    }
    ax = ax >= 0.f ? ax : 0.01f * ax;
    ay = ay >= 0.f ? ay : 0.01f * ay;
    float ss = ax * ax + ay * ay;
#pragma unroll
    for (int o = 32; o > 0; o >>= 1) ss += __shfl_xor(ss, o);
    float inv = 1.f / fmaxf(sqrtf(ss), 1e-12f);
    half2t hv = { (_Float16)(ax * inv), (_Float16)(ay * inv) };
    *(half2t*)(enc_h + (size_t)row * 128 + lane * 2) = hv;
}

// ---------------- MFMA attention + mean + out_proj + fused tar gather ----------------

__global__ __launch_bounds__(256) void attn_mfma_kernel(
    const _Float16* __restrict__ qkv, const float* __restrict__ outw,
    const float* __restrict__ outb, const _Float16* __restrict__ enc_h,
    const int* __restrict__ data_poi, float* __restrict__ out)
{
    const int b = blockIdx.x;
    const int wave = threadIdx.x >> 6;   // head
    const int lane = threadIdx.x & 63;
    const int l15 = lane & 15;
    const int quad = lane >> 4;
    __shared__ _Float16 pP[NHEADS][64][72];
    __shared__ _Float16 vT[NHEADS][32][72];
    __shared__ float ob[128];
    const _Float16* base = qkv + (size_t)b * SEQL * 384;

    // stage V^T: lane m scatters its V row
    {
        const _Float16* vrow = base + (size_t)lane * 384 + 256 + wave * 32;
        half8 v0 = *(const half8*)(vrow);
        half8 v1 = *(const half8*)(vrow + 8);
        half8 v2 = *(const half8*)(vrow + 16);
        half8 v3 = *(const half8*)(vrow + 24);
#pragma unroll
        for (int j = 0; j < 8; ++j) {
            vT[wave][j][lane]      = v0[j];
            vT[wave][j + 8][lane]  = v1[j];
            vT[wave][j + 16][lane] = v2[j];
            vT[wave][j + 24][lane] = v3[j];
        }
    }

    // Q / K fragments straight from global (A-layout: row=l15, k=quad*8+j)
    half8 qf[4], kf[4];
#pragma unroll
    for (int t = 0; t < 4; ++t) {
        qf[t] = *(const half8*)(base + (size_t)(t * 16 + l15) * 384 + wave * 32 + quad * 8);
        kf[t] = *(const half8*)(base + (size_t)(t * 16 + l15) * 384 + 128 + wave * 32 + quad * 8);
    }

    f32x4 S[4][4];
#pragma unroll
    for (int lt = 0; lt < 4; ++lt)
#pragma unroll
        for (int mt = 0; mt < 4; ++mt) S[lt][mt] = (f32x4){0.f, 0.f, 0.f, 0.f};
#pragma unroll
    for (int lt = 0; lt < 4; ++lt)
#pragma unroll
        for (int mt = 0; mt < 4; ++mt)
            S[lt][mt] = __builtin_amdgcn_mfma_f32_16x16x32_f16(qf[lt], kf[mt], S[lt][mt], 0, 0, 0);

    const float scale = 0.17677669529663687f;  // 1/sqrt(32)
#pragma unroll
    for (int lt = 0; lt < 4; ++lt) {
#pragma unroll
        for (int r = 0; r < 4; ++r) {
            float m0 = -1e30f;
#pragma unroll
            for (int mt = 0; mt < 4; ++mt) {
                S[lt][mt][r] *= scale;
                m0 = fmaxf(m0, S[lt][mt][r]);
            }
#pragma unroll
            for (int o = 1; o < 16; o <<= 1) m0 = fmaxf(m0, __shfl_xor(m0, o));
            float s0 = 0.f;
#pragma unroll
            for (int mt = 0; mt < 4; ++mt) {
                float p = __expf(S[lt][mt][r] - m0);
                S[lt][mt][r] = p;
                s0 += p;
            }
#pragma unroll
            for (int o = 1; o < 16; o <<= 1) s0 += __shfl_xor(s0, o);
            float inv = 1.f / s0;
#pragma unroll
            for (int mt = 0; mt < 4; ++mt)
                pP[wave][lt * 16 + quad * 4 + r][mt * 16 + l15] = (_Float16)(S[lt][mt][r] * inv);
        }
    }
    __syncthreads();

    // O = P V : contraction over m (64) in 2 steps
    f32x4 O[4][2];
#pragma unroll
    for (int lt = 0; lt < 4; ++lt)
#pragma unroll
        for (int jt = 0; jt < 2; ++jt) O[lt][jt] = (f32x4){0.f, 0.f, 0.f, 0.f};
#pragma unroll
    for (int kh = 0; kh < 2; ++kh) {
        half8 vf[2];
#pragma unroll
        for (int jt = 0; jt < 2; ++jt)
            vf[jt] = *(const half8*)&vT[wave][jt * 16 + l15][kh * 32 + quad * 8];
#pragma unroll
        for (int lt = 0; lt < 4; ++lt) {
            half8 pf = *(const half8*)&pP[wave][lt * 16 + l15][kh * 32 + quad * 8];
#pragma unroll
            for (int jt = 0; jt < 2; ++jt)
                O[lt][jt] = __builtin_amdgcn_mfma_f32_16x16x32_f16(pf, vf[jt], O[lt][jt], 0, 0, 0);
        }
    }

    // mean over the 64 query rows -> ob[head*32 + j]
#pragma unroll
    for (int jt = 0; jt < 2; ++jt) {
        float part = 0.f;
#pragma unroll
        for (int lt = 0; lt < 4; ++lt)
#pragma unroll
            for (int r = 0; r < 4; ++r) part += O[lt][jt][r];
        part += __shfl_xor(part, 16);
        part += __shfl_xor(part, 32);
        if (quad == 0) ob[wave * 32 + jt * 16 + l15] = part * (1.f / 64.f);
    }
    __syncthreads();

    int t = threadIdx.x;
    if (t < 128) {
        float val = outb[t];
        const float* wrow = outw + (size_t)t * 128;
#pragma unroll 8
        for (int k4 = 0; k4 < 32; ++k4) {
            float4 wv = *(const float4*)(wrow + k4 * 4);
            val += wv.x * ob[k4 * 4] + wv.y * ob[k4 * 4 + 1]
                 + wv.z * ob[k4 * 4 + 2] + wv.w * ob[k4 * 4 + 3];
        }
        out[(size_t)b * 128 + t] = val;
    } else {
        // fused tar_embed gather (fp16 enc)
        int j = t - 128;
        out[(size_t)(BATCH + b) * 128 + j] = (float)enc_h[(size_t)data_poi[b] * 128 + j];
    }
}

// ---------------- launch ----------------

extern "C" void kernel_launch(void* const* d_in, const int* in_sizes, int n_in,
                              void* d_out, int out_size, void* d_ws, size_t ws_size,
                              hipStream_t stream)
{
    const float* poi      = (const float*)d_in[0];
    const int*   edges    = (const int*)d_in[1];
    const float* dvec     = (const float*)d_in[2];
    const int*   data_poi = (const int*)d_in[3];
    const int*   data_x   = (const int*)d_in[4];
    const float* lin_w    = (const float*)d_in[5];
    const float* lin_b    = (const float*)d_in[6];
    const float* inw      = (const float*)d_in[7];
    const float* inb      = (const float*)d_in[8];
    const float* outw     = (const float*)d_in[9];
    const float* outb     = (const float*)d_in[10];
    const int* e0 = edges;
    const int* e1 = edges + NEDGE;

    char* ws = (char*)d_ws;
    size_t off = 0;
    auto alloc = [&](size_t bytes) -> void* {
        void* p = ws + off;
        off = (off + bytes + 255) & ~(size_t)255;
        return p;
    };
    int*      offs   = (int*)     alloc((NPOI + 1) * 4);
    int*      bcur   = (int*)     alloc(NB * 4);
    float*    rd     = (float*)   alloc(NPOI * 4);
    unsigned* ew     = (unsigned*)alloc((size_t)EAUG * 4);
    _Float16* enc_h  = (_Float16*)alloc((size_t)NPOI * 128 * 2);
    _Float16* linw_h = (_Float16*)alloc((size_t)2 * 128 * 128 * 2);
    _Float16* inw_h  = (_Float16*)alloc((size_t)384 * 128 * 2);
    char*     big    = (char*)    alloc(50ull * 1024 * 1024);
    // aliases inside the big region (lifetimes strictly ordered):
    //   poi_h   [ 0, 12.8 MB)  — cvt -> GEMM1
    //   staging [16, 32.1 MB)  — partition -> csr_sort
    //   hbuf    [33, 45.8 MB)  — GEMM1/2 -> aggregate
    //   qkv_h   [ 0, 25.2 MB)  — qkv GEMM (after all above dead) -> attn
    _Float16* poi_h   = (_Float16*)big;
    u64*      staging = (u64*)(big + 16ull * 1024 * 1024);
    _Float16* hbuf    = (_Float16*)(big + 33ull * 1024 * 1024);
    _Float16* qkv_h   = (_Float16*)big;

    cvt_all_kernel<<<(CVT_TOT + 255) / 256, 256, 0, stream>>>(
        poi, lin_w, inw, poi_h, linw_h, inw_h, bcur);

    partition_kernel<<<P1_BLOCKS, 256, 0, stream>>>(e0, e1, dvec, bcur, staging);
    csr_sort_kernel<<<NB, 256, 0, stream>>>(staging, bcur, rd, offs, ew);

    // 2 graph-conv layers (rd folded into h via GEMM epilogue row-scale)
    gemm_mfma_f16<<<dim3(2, (NPOI + 63) / 64), 256, 0, stream>>>(
        poi_h, nullptr, linw_h, lin_b, rd, hbuf, NPOI, 128);
    aggregate_kernel<<<NPOI, 64, 0, stream>>>(hbuf, offs, ew, enc_h);
    gemm_mfma_f16<<<dim3(2, (NPOI + 63) / 64), 256, 0, stream>>>(
        enc_h, nullptr, linw_h + 128 * 128, lin_b + 128, rd, hbuf, NPOI, 128);
    aggregate_kernel<<<NPOI, 64, 0, stream>>>(hbuf, offs, ew, enc_h);

    // attention (qkv gemm fp16 -> MFMA attn + mean + out_proj + tar -> d_out)
    gemm_mfma_f16<<<dim3(6, BATCH * SEQL / 64), 256, 0, stream>>>(
        enc_h, data_x, inw_h, inb, nullptr, qkv_h, BATCH * SEQL, 384);
    attn_mfma_kernel<<<BATCH, 256, 0, stream>>>(qkv_h, outw, outb, enc_h, data_poi,
                                                (float*)d_out);
}

// Round 17
// 270.494 us; speedup vs baseline: 1.0825x; 1.0480x over previous
//
#include <hip/hip_runtime.h>
#include <hip/hip_fp16.h>

#define NPOI 50000
#define EMB 128
#define NEDGE 800000
#define EAUG (2 * NEDGE + NPOI)
#define BATCH 512
#define SEQL 64
#define NHEADS 4
#define NB 196                              // 256-node buckets
#define P1_BLOCKS ((NEDGE + 2047) / 2048)   // 391
#define SLAB_CAP 10240
#define BUCKET_CAP 10240

#define N4_LIN (2 * 128 * 128 / 4)          // 8192
#define N4_INW (384 * 128 / 4)              // 12288
#define CVTW_TOT (N4_LIN + N4_INW)          // 20480
#define CVTW_BLOCKS ((CVTW_TOT + 255) / 256)  // 80
#define GB1_Y ((NPOI + 63) / 64)            // 782
#define GB1 (2 * GB1_Y)                     // 1564
#define FUSED_BLOCKS (P1_BLOCKS + GB1 + CVTW_BLOCKS)

typedef _Float16 half8 __attribute__((ext_vector_type(8)));
typedef _Float16 half4 __attribute__((ext_vector_type(4)));
typedef _Float16 half2t __attribute__((ext_vector_type(2)));
typedef float f32x4 __attribute__((ext_vector_type(4)));
typedef unsigned long long u64;

union HBits { _Float16 h; unsigned short u; };

struct __align__(16) SmemP {
    u64 stg[4096];
    int lh[NB], lbase[NB], gb[NB];
    int sc[256];
};
struct __align__(16) SmemG {
    _Float16 Asl[64][136];
    _Float16 Bsl[64][136];
};
#define SMEM_BYTES (sizeof(SmemP) > sizeof(SmemG) ? sizeof(SmemP) : sizeof(SmemG))

// ---------------- fused launch 1 bodies: partition | gemm1(fp32 in) | weight cvt ----------------

__device__ void partition_body(char* smem_raw, int bb,
                               const int* __restrict__ e0, const int* __restrict__ e1,
                               const float* __restrict__ dv, int* __restrict__ bcur,
                               u64* __restrict__ staging)
{
    SmemP& S = *(SmemP*)smem_raw;
    const int t = threadIdx.x;
    const int blockBase = bb * 2048;
    for (int j = t; j < NB; j += 256) S.lh[j] = 0;
    __syncthreads();

    u64 vals[16];
    unsigned br[16];
#pragma unroll
    for (int i = 0; i < 8; ++i) {
        br[2 * i] = 0xFFFFFFFFu;
        br[2 * i + 1] = 0xFFFFFFFFu;
        int g = blockBase + i * 256 + t;
        if (g < NEDGE) {
            int s = e0[g], d = e1[g];
            unsigned db = __float_as_uint(dv[g]);
            vals[2 * i]     = ((u64)s << 48) | ((u64)d << 32) | db;
            vals[2 * i + 1] = ((u64)d << 48) | ((u64)s << 32) | db;
            int bs = s >> 8, bd = d >> 8;
            int rs = atomicAdd(&S.lh[bs], 1);
            int rd_ = atomicAdd(&S.lh[bd], 1);
            br[2 * i]     = ((unsigned)bs << 16) | (unsigned)rs;
            br[2 * i + 1] = ((unsigned)bd << 16) | (unsigned)rd_;
        }
    }
    __syncthreads();
    S.sc[t] = (t < NB) ? S.lh[t] : 0;
    __syncthreads();
    for (int o = 1; o < 256; o <<= 1) {
        int u = (t >= o) ? S.sc[t - o] : 0;
        __syncthreads();
        S.sc[t] += u;
        __syncthreads();
    }
    if (t < NB) {
        S.lbase[t] = S.sc[t] - S.lh[t];
        S.gb[t] = (S.lh[t] > 0) ? (t * SLAB_CAP + atomicAdd(&bcur[t], S.lh[t])) : 0;
    }
    __syncthreads();
#pragma unroll
    for (int i = 0; i < 16; ++i) {
        if (br[i] != 0xFFFFFFFFu) {
            int b = br[i] >> 16, r = br[i] & 0xFFFF;
            S.stg[S.lbase[b] + r] = vals[i];
        }
    }
    __syncthreads();
    const int total = S.sc[255];
    for (int j = t; j < total; j += 256) {
        u64 v = S.stg[j];
        int b = (int)(v >> 56);
        staging[(size_t)S.gb[b] + (unsigned)(j - S.lbase[b])] = v;
    }
}

// layer-1 GEMM: hbuf = poi(fp32) @ lin_w0(fp32)^T + lin_b0, converted to fp16 in staging.
// rd-fold NOT applied here (rd not computed yet) — csr_sort tail scales hbuf rows.
__device__ void gemm1_body(char* smem_raw, int g, const float* __restrict__ A,
                           const float* __restrict__ B, const float* __restrict__ bias,
                           _Float16* __restrict__ C)
{
    SmemG& S = *(SmemG*)smem_raw;
    const int tid = threadIdx.x;
    const int n0 = (g / GB1_Y) * 64;
    const int m0 = (g % GB1_Y) * 64;

#pragma unroll
    for (int i = 0; i < 8; ++i) {
        int u = i * 256 + tid;
        int r = u >> 5, c = u & 31;
        int row = m0 + r;
        int ar = (row < NPOI) ? row : 0;
        float4 v = *(const float4*)(A + (size_t)ar * 128 + c * 4);
        half4 h = { (_Float16)v.x, (_Float16)v.y, (_Float16)v.z, (_Float16)v.w };
        *(half4*)&S.Asl[r][c * 4] = h;
        float4 bv = *(const float4*)(B + (size_t)(n0 + r) * 128 + c * 4);
        half4 hb = { (_Float16)bv.x, (_Float16)bv.y, (_Float16)bv.z, (_Float16)bv.w };
        *(half4*)&S.Bsl[r][c * 4] = hb;
    }
    __syncthreads();

    const int wave = tid >> 6;
    const int lane = tid & 63;
    const int l15 = lane & 15;
    const int quad = lane >> 4;

    f32x4 acc[4];
#pragma unroll
    for (int mt = 0; mt < 4; ++mt) acc[mt] = (f32x4){0.f, 0.f, 0.f, 0.f};
#pragma unroll
    for (int ks = 0; ks < 4; ++ks) {
        half8 bfrag = *(const half8*)&S.Bsl[wave * 16 + l15][quad * 8 + ks * 32];
#pragma unroll
        for (int mt = 0; mt < 4; ++mt) {
            half8 afrag = *(const half8*)&S.Asl[mt * 16 + l15][quad * 8 + ks * 32];
            acc[mt] = __builtin_amdgcn_mfma_f32_16x16x32_f16(afrag, bfrag, acc[mt], 0, 0, 0);
        }
    }

    const int col = wave * 16 + l15;
    const float bv = bias[n0 + col];
    __syncthreads();
#pragma unroll
    for (int mt = 0; mt < 4; ++mt)
#pragma unroll
        for (int r = 0; r < 4; ++r)
            S.Asl[mt * 16 + quad * 4 + r][col] = (_Float16)(acc[mt][r] + bv);
    __syncthreads();
#pragma unroll
    for (int i = 0; i < 2; ++i) {
        int u = i * 256 + tid;
        int r = u >> 3, c = u & 7;
        int m = m0 + r;
        if (m < NPOI)
            *(half8*)(C + (size_t)m * 128 + n0 + c * 8) = *(const half8*)&S.Asl[r][c * 8];
    }
}

__device__ void cvtw_body(int g, const float* __restrict__ linw, const float* __restrict__ inw,
                          _Float16* __restrict__ linw_h, _Float16* __restrict__ inw_h)
{
    int i = g * 256 + threadIdx.x;
    if (i >= CVTW_TOT) return;
    const float* src; _Float16* dst; int j = i;
    if (i < N4_LIN) { src = linw; dst = linw_h; }
    else { j = i - N4_LIN; src = inw; dst = inw_h; }
    float4 v = ((const float4*)src)[j];
    half4 h = { (_Float16)v.x, (_Float16)v.y, (_Float16)v.z, (_Float16)v.w };
    ((half4*)dst)[j] = h;
}

__global__ __launch_bounds__(256) void fused1_kernel(
    const int* __restrict__ e0, const int* __restrict__ e1, const float* __restrict__ dv,
    int* __restrict__ bcur, u64* __restrict__ staging,
    const float* __restrict__ poi, const float* __restrict__ linw,
    const float* __restrict__ lin_b, _Float16* __restrict__ hbuf,
    const float* __restrict__ inw, _Float16* __restrict__ linw_h,
    _Float16* __restrict__ inw_h)
{
    __shared__ __align__(16) char smem_raw[SMEM_BYTES];
    int bx = blockIdx.x;
    if (bx < P1_BLOCKS)
        partition_body(smem_raw, bx, e0, e1, dv, bcur, staging);
    else if (bx < P1_BLOCKS + GB1)
        gemm1_body(smem_raw, bx - P1_BLOCKS, poi, linw, lin_b, hbuf);
    else
        cvtw_body(bx - P1_BLOCKS - GB1, linw, inw, linw_h, inw_h);
}

// ---------------- per-bucket counting sort + rd + offs + weights -> packed CSR ----------------
// bcur holds per-bucket counts (memset 0 + partition atomics). Tail: scale layer-1 h rows by rd.

__global__ __launch_bounds__(256) void csr_sort_kernel(
    const u64* __restrict__ staging, const int* __restrict__ bcur,
    float* __restrict__ rd, int* __restrict__ offs, unsigned* __restrict__ ew,
    _Float16* __restrict__ hbuf)
{
    const int k = blockIdx.x;
    const int node0 = k * 256;
    __shared__ unsigned outb[BUCKET_CAP];
    __shared__ int cnt[256], base2[256];
    __shared__ float rdl[256];
    __shared__ int bb_sh;
    const int t = threadIdx.x;
    const int node = node0 + t;
    // bucket base = sum over previous buckets of (count + 256 self loops)
    {
        int partial = 0;
        for (int j = t; j < k; j += 256) partial += bcur[j] + 256;
        base2[t] = partial;
        __syncthreads();
        for (int o = 128; o > 0; o >>= 1) {
            if (t < o) base2[t] += base2[t + o];
            __syncthreads();
        }
        if (t == 0) bb_sh = base2[0];
        __syncthreads();
    }
    const int bucketbase = bb_sh;
    __syncthreads();
    cnt[t] = 0;
    __syncthreads();
    const int sb = k * SLAB_CAP;
    const int n = bcur[k];
    for (int j = t; j < n; j += 256)
        atomicAdd(&cnt[(int)(staging[sb + j] >> 48) & 255], 1);
    __syncthreads();
    int rowsz = (node < NPOI) ? cnt[t] + 1 : 0;
    if (node < NPOI) {
        float r_ = rsqrtf((float)rowsz);
        rd[node] = r_;
        rdl[t] = r_;
    } else rdl[t] = 0.f;
    base2[t] = rowsz;
    __syncthreads();
    for (int o = 1; o < 256; o <<= 1) {
        int u = (t >= o) ? base2[t - o] : 0;
        __syncthreads();
        base2[t] += u;
        __syncthreads();
    }
    int myexc = base2[t] - rowsz;
    __syncthreads();
    base2[t] = myexc;
    cnt[t] = 0;
    if (node < NPOI) {
        offs[node] = bucketbase + myexc;
        if (node == NPOI - 1) offs[NPOI] = bucketbase + myexc + rowsz;
    }
    __syncthreads();
    for (int j = t; j < n; j += 256) {
        u64 e = staging[sb + j];
        int sl = (int)(e >> 48) & 255;
        int d = (int)(e >> 32) & 0xFFFF;
        float dist = __uint_as_float((unsigned)e);
        float w = rdl[sl] * expf(-dist * dist);      // rd[d] folded into h'
        HBits cv; cv.h = (_Float16)w;
        int r = atomicAdd(&cnt[sl], 1);
        outb[base2[sl] + r] = ((unsigned)d << 16) | cv.u;
    }
    __syncthreads();
    if (node < NPOI) {   // self loop: w' = rd[s] (h'[s] carries the other rd[s])
        HBits cv; cv.h = (_Float16)rdl[t];
        outb[base2[t] + cnt[t]] = ((unsigned)node << 16) | cv.u;
    }
    __syncthreads();
    const int nn = (node0 + 256 <= NPOI) ? 256 : (NPOI - node0);
    const int ntot = n + nn;
    for (int j = t; j < ntot; j += 256) ew[bucketbase + j] = outb[j];   // coalesced
    // tail: apply layer-1 rd-fold to this bucket's h rows (gemm1 ran before rd existed)
    __syncthreads();
    for (int rr = (t >> 4); rr < nn; rr += 16) {
        float s = rdl[rr];
        half8* p = (half8*)(hbuf + (size_t)(node0 + rr) * 128 + (t & 15) * 8);
        half8 v = *p;
#pragma unroll
        for (int j = 0; j < 8; ++j) v[j] = (_Float16)((float)v[j] * s);
        *p = v;
    }
}

// ---------------- fp16 MFMA GEMM, 64x64 tile: C = rs(row)·(A(gathered) @ B^T + bias) ----------

__global__ __launch_bounds__(256) void gemm_mfma_f16(
    const _Float16* __restrict__ A, const int* __restrict__ gidx,
    const _Float16* __restrict__ B, const float* __restrict__ bias,
    const float* __restrict__ rs,
    _Float16* __restrict__ C, int M, int N)
{
    __shared__ _Float16 Asl[64][136];
    __shared__ _Float16 Bsl[64][136];
    const int tid = threadIdx.x;
    const int n0 = blockIdx.x * 64;
    const int m0 = blockIdx.y * 64;

#pragma unroll
    for (int i = 0; i < 4; ++i) {
        int u = i * 256 + tid;
        int r = u >> 4;
        int c = u & 15;
        int row = m0 + r;
        int ar = (row < M) ? (gidx ? gidx[row] : row) : 0;
        *(float4*)&Asl[r][c * 8] = *(const float4*)(A + (size_t)ar * 128 + c * 8);
        *(float4*)&Bsl[r][c * 8] = *(const float4*)(B + (size_t)(n0 + r) * 128 + c * 8);
    }
    __syncthreads();

    const int wave = tid >> 6;
    const int lane = tid & 63;
    const int l15 = lane & 15;
    const int quad = lane >> 4;

    f32x4 acc[4];
#pragma unroll
    for (int mt = 0; mt < 4; ++mt) acc[mt] = (f32x4){0.f, 0.f, 0.f, 0.f};

#pragma unroll
    for (int ks = 0; ks < 4; ++ks) {
        half8 bfrag = *(const half8*)&Bsl[wave * 16 + l15][quad * 8 + ks * 32];
#pragma unroll
        for (int mt = 0; mt < 4; ++mt) {
            half8 afrag = *(const half8*)&Asl[mt * 16 + l15][quad * 8 + ks * 32];
            acc[mt] = __builtin_amdgcn_mfma_f32_16x16x32_f16(afrag, bfrag, acc[mt], 0, 0, 0);
        }
    }

    const int col = wave * 16 + l15;
    const float bv = bias[n0 + col];
    __syncthreads();
#pragma unroll
    for (int mt = 0; mt < 4; ++mt)
#pragma unroll
        for (int r = 0; r < 4; ++r) {
            int m = m0 + mt * 16 + quad * 4 + r;
            float v = acc[mt][r] + bv;
            if (rs) { int mm = (m < M) ? m : 0; v *= rs[mm]; }
            Asl[mt * 16 + quad * 4 + r][col] = (_Float16)v;
        }
    __syncthreads();
#pragma unroll
    for (int i = 0; i < 2; ++i) {
        int u = i * 256 + tid;
        int r = u >> 3;
        int c = u & 7;
        int m = m0 + r;
        if (m < M)
            *(half8*)(C + (size_t)m * N + n0 + c * 8) = *(const half8*)&Asl[r][c * 8];
    }
}

// ---------------- CSR aggregate + leaky-relu + L2 normalize ----------------

__global__ __launch_bounds__(64) void aggregate_kernel(
    const _Float16* __restrict__ h, const int* __restrict__ offs,
    const unsigned* __restrict__ ew, _Float16* __restrict__ enc_h)
{
    const int row = blockIdx.x;
    const int lane = threadIdx.x;
    const int beg = offs[row];
    const int end = offs[row + 1];
    float ax = 0.f, ay = 0.f;
#pragma unroll 8
    for (int e = beg; e < end; ++e) {
        unsigned p = ew[e];
        HBits cv; cv.u = (unsigned short)(p & 0xffffu);
        float w = (float)cv.h;
        int d = p >> 16;
        half2t hv = *(const half2t*)(h + (size_t)d * 128 + lane * 2);
        ax += w * (float)hv[0];
        ay += w * (float)hv[1];
    }
    ax = ax >= 0.f ? ax : 0.01f * ax;
    ay = ay >= 0.f ? ay : 0.01f * ay;
    float ss = ax * ax + ay * ay;
#pragma unroll
    for (int o = 32; o > 0; o >>= 1) ss += __shfl_xor(ss, o);
    float inv = 1.f / fmaxf(sqrtf(ss), 1e-12f);
    half2t hv = { (_Float16)(ax * inv), (_Float16)(ay * inv) };
    *(half2t*)(enc_h + (size_t)row * 128 + lane * 2) = hv;
}

// ---------------- MFMA attention + mean + out_proj + fused tar gather ----------------

__global__ __launch_bounds__(256) void attn_mfma_kernel(
    const _Float16* __restrict__ qkv, const float* __restrict__ outw,
    const float* __restrict__ outb, const _Float16* __restrict__ enc_h,
    const int* __restrict__ data_poi, float* __restrict__ out)
{
    const int b = blockIdx.x;
    const int wave = threadIdx.x >> 6;   // head
    const int lane = threadIdx.x & 63;
    const int l15 = lane & 15;
    const int quad = lane >> 4;
    __shared__ _Float16 pP[NHEADS][64][72];
    __shared__ _Float16 vT[NHEADS][32][72];
    __shared__ float ob[128];
    const _Float16* base = qkv + (size_t)b * SEQL * 384;

    {
        const _Float16* vrow = base + (size_t)lane * 384 + 256 + wave * 32;
        half8 v0 = *(const half8*)(vrow);
        half8 v1 = *(const half8*)(vrow + 8);
        half8 v2 = *(const half8*)(vrow + 16);
        half8 v3 = *(const half8*)(vrow + 24);
#pragma unroll
        for (int j = 0; j < 8; ++j) {
            vT[wave][j][lane]      = v0[j];
            vT[wave][j + 8][lane]  = v1[j];
            vT[wave][j + 16][lane] = v2[j];
            vT[wave][j + 24][lane] = v3[j];
        }
    }

    half8 qf[4], kf[4];
#pragma unroll
    for (int t = 0; t < 4; ++t) {
        qf[t] = *(const half8*)(base + (size_t)(t * 16 + l15) * 384 + wave * 32 + quad * 8);
        kf[t] = *(const half8*)(base + (size_t)(t * 16 + l15) * 384 + 128 + wave * 32 + quad * 8);
    }

    f32x4 S[4][4];
#pragma unroll
    for (int lt = 0; lt < 4; ++lt)
#pragma unroll
        for (int mt = 0; mt < 4; ++mt) S[lt][mt] = (f32x4){0.f, 0.f, 0.f, 0.f};
#pragma unroll
    for (int lt = 0; lt < 4; ++lt)
#pragma unroll
        for (int mt = 0; mt < 4; ++mt)
            S[lt][mt] = __builtin_amdgcn_mfma_f32_16x16x32_f16(qf[lt], kf[mt], S[lt][mt], 0, 0, 0);

    const float scale = 0.17677669529663687f;  // 1/sqrt(32)
#pragma unroll
    for (int lt = 0; lt < 4; ++lt) {
#pragma unroll
        for (int r = 0; r < 4; ++r) {
            float m0 = -1e30f;
#pragma unroll
            for (int mt = 0; mt < 4; ++mt) {
                S[lt][mt][r] *= scale;
                m0 = fmaxf(m0, S[lt][mt][r]);
            }
#pragma unroll
            for (int o = 1; o < 16; o <<= 1) m0 = fmaxf(m0, __shfl_xor(m0, o));
            float s0 = 0.f;
#pragma unroll
            for (int mt = 0; mt < 4; ++mt) {
                float p = __expf(S[lt][mt][r] - m0);
                S[lt][mt][r] = p;
                s0 += p;
            }
#pragma unroll
            for (int o = 1; o < 16; o <<= 1) s0 += __shfl_xor(s0, o);
            float inv = 1.f / s0;
#pragma unroll
            for (int mt = 0; mt < 4; ++mt)
                pP[wave][lt * 16 + quad * 4 + r][mt * 16 + l15] = (_Float16)(S[lt][mt][r] * inv);
        }
    }
    __syncthreads();

    f32x4 O[4][2];
#pragma unroll
    for (int lt = 0; lt < 4; ++lt)
#pragma unroll
        for (int jt = 0; jt < 2; ++jt) O[lt][jt] = (f32x4){0.f, 0.f, 0.f, 0.f};
#pragma unroll
    for (int kh = 0; kh < 2; ++kh) {
        half8 vf[2];
#pragma unroll
        for (int jt = 0; jt < 2; ++jt)
            vf[jt] = *(const half8*)&vT[wave][jt * 16 + l15][kh * 32 + quad * 8];
#pragma unroll
        for (int lt = 0; lt < 4; ++lt) {
            half8 pf = *(const half8*)&pP[wave][lt * 16 + l15][kh * 32 + quad * 8];
#pragma unroll
            for (int jt = 0; jt < 2; ++jt)
                O[lt][jt] = __builtin_amdgcn_mfma_f32_16x16x32_f16(pf, vf[jt], O[lt][jt], 0, 0, 0);
        }
    }

#pragma unroll
    for (int jt = 0; jt < 2; ++jt) {
        float part = 0.f;
#pragma unroll
        for (int lt = 0; lt < 4; ++lt)
#pragma unroll
            for (int r = 0; r < 4; ++r) part += O[lt][jt][r];
        part += __shfl_xor(part, 16);
        part += __shfl_xor(part, 32);
        if (quad == 0) ob[wave * 32 + jt * 16 + l15] = part * (1.f / 64.f);
    }
    __syncthreads();

    int t = threadIdx.x;
    if (t < 128) {
        float val = outb[t];
        const float* wrow = outw + (size_t)t * 128;
#pragma unroll 8
        for (int k4 = 0; k4 < 32; ++k4) {
            float4 wv = *(const float4*)(wrow + k4 * 4);
            val += wv.x * ob[k4 * 4] + wv.y * ob[k4 * 4 + 1]
                 + wv.z * ob[k4 * 4 + 2] + wv.w * ob[k4 * 4 + 3];
        }
        out[(size_t)b * 128 + t] = val;
    } else {
        int j = t - 128;
        out[(size_t)(BATCH + b) * 128 + j] = (float)enc_h[(size_t)data_poi[b] * 128 + j];
    }
}

// ---------------- launch ----------------

extern "C" void kernel_launch(void* const* d_in, const int* in_sizes, int n_in,
                              void* d_out, int out_size, void* d_ws, size_t ws_size,
                              hipStream_t stream)
{
    const float* poi      = (const float*)d_in[0];
    const int*   edges    = (const int*)d_in[1];
    const float* dvec     = (const float*)d_in[2];
    const int*   data_poi = (const int*)d_in[3];
    const int*   data_x   = (const int*)d_in[4];
    const float* lin_w    = (const float*)d_in[5];
    const float* lin_b    = (const float*)d_in[6];
    const float* inw      = (const float*)d_in[7];
    const float* inb      = (const float*)d_in[8];
    const float* outw     = (const float*)d_in[9];
    const float* outb     = (const float*)d_in[10];
    const int* e0 = edges;
    const int* e1 = edges + NEDGE;

    char* ws = (char*)d_ws;
    size_t off = 0;
    auto alloc = [&](size_t bytes) -> void* {
        void* p = ws + off;
        off = (off + bytes + 255) & ~(size_t)255;
        return p;
    };
    int*      offs   = (int*)     alloc((NPOI + 1) * 4);
    int*      bcur   = (int*)     alloc(NB * 4);
    float*    rd     = (float*)   alloc(NPOI * 4);
    unsigned* ew     = (unsigned*)alloc((size_t)EAUG * 4);
    _Float16* enc_h  = (_Float16*)alloc((size_t)NPOI * 128 * 2);
    _Float16* linw_h = (_Float16*)alloc((size_t)2 * 128 * 128 * 2);
    _Float16* inw_h  = (_Float16*)alloc((size_t)384 * 128 * 2);
    char*     big    = (char*)    alloc(50ull * 1024 * 1024);
    // aliases inside the big region (lifetimes strictly ordered):
    //   staging [16, 32.1 MB)  — fused1(partition) -> csr_sort
    //   hbuf    [33, 45.8 MB)  — fused1(gemm1)/gemm2 -> aggregate
    //   qkv_h   [ 0, 25.2 MB)  — qkv GEMM (after staging dead) -> attn
    u64*      staging = (u64*)(big + 16ull * 1024 * 1024);
    _Float16* hbuf    = (_Float16*)(big + 33ull * 1024 * 1024);
    _Float16* qkv_h   = (_Float16*)big;

    hipMemsetAsync(bcur, 0, NB * 4, stream);

    // fused: edge partition ∥ layer-1 GEMM (fp32 in) ∥ weight fp16 conversion
    fused1_kernel<<<FUSED_BLOCKS, 256, 0, stream>>>(
        e0, e1, dvec, bcur, staging, poi, lin_w, lin_b, hbuf, inw, linw_h, inw_h);

    csr_sort_kernel<<<NB, 256, 0, stream>>>(staging, bcur, rd, offs, ew, hbuf);

    aggregate_kernel<<<NPOI, 64, 0, stream>>>(hbuf, offs, ew, enc_h);
    gemm_mfma_f16<<<dim3(2, (NPOI + 63) / 64), 256, 0, stream>>>(
        enc_h, nullptr, linw_h + 128 * 128, lin_b + 128, rd, hbuf, NPOI, 128);
    aggregate_kernel<<<NPOI, 64, 0, stream>>>(hbuf, offs, ew, enc_h);

    gemm_mfma_f16<<<dim3(6, BATCH * SEQL / 64), 256, 0, stream>>>(
        enc_h, data_x, inw_h, inb, nullptr, qkv_h, BATCH * SEQL, 384);
    attn_mfma_kernel<<<BATCH, 256, 0, stream>>>(qkv_h, outw, outb, enc_h, data_poi,
                                                (float*)d_out);
}